// Round 4
// baseline (76.821 us; speedup 1.0000x reference)
//
#include <hip/hip_runtime.h>

#define TPB 256

// Sum over the 4 edges (A->B) of CCW polygon V of (t1-t0)*cross(A,B), where
// [t0,t1] ⊆ [0,1] is the parameter interval of the edge inside the CCW clip
// quad given by lines d(X) = ex*X.y - ey*X.x - c0 >= 0.  Summing this for
// (P-edges clipped by Q) and (Q-edges clipped by P) gives 2*area(P∩Q).
//
// Interval form: d(t) = dA - t*D with D = dA-dB.  D>0 -> t is an upper bound,
// D<0 -> t is a lower bound.  PROT=true (P-pass): degenerate |D|<eps keeps the
// edge when dA>=0 (ties count as inside); PROT=false (Q-pass): degenerate
// edges are dropped (ties outside) so coincident boundaries aren't counted twice.
template<bool PROT>
__device__ __forceinline__ float edge_pieces(
    const float (&vx)[4], const float (&vy)[4],
    const float (&ex)[4], const float (&ey)[4], const float (&c0)[4])
{
    float d[4][4];
    #pragma unroll
    for (int i = 0; i < 4; ++i)
        #pragma unroll
        for (int k = 0; k < 4; ++k)
            d[i][k] = fmaf(ex[k], vy[i], -fmaf(ey[k], vx[i], c0[k]));

    float sum = 0.f;
    #pragma unroll
    for (int i = 0; i < 4; ++i) {
        const int j = (i + 1) & 3;
        const float cr = fmaf(vx[i], vy[j], -(vy[i] * vx[j]));
        float lo = 0.f, hi = 1.f;
        #pragma unroll
        for (int k = 0; k < 4; ++k) {
            const float dA = d[i][k], dB = d[j][k];
            const float D  = dA - dB;
            float Dt;
            if (PROT) {
                const float eps = (dA >= 0.f) ? -1e-12f : 1e-12f;
                Dt = (fabsf(D) < 1e-12f) ? eps : D;
            } else {
                Dt = (fabsf(D) < 1e-12f) ? 1e-12f : D;
            }
            const float t  = dA * __builtin_amdgcn_rcpf(Dt);
            const bool  up = Dt > 0.f;
            const float h2 = fminf(hi, t);
            const float l2 = fmaxf(lo, t);
            hi = up ? h2 : hi;
            lo = up ? lo : l2;
        }
        sum = fmaf(fmaxf(hi - lo, 0.f), cr, sum);
    }
    return sum;
}

__device__ __forceinline__ void make_lines(
    const float (&vx)[4], const float (&vy)[4],
    float (&ex)[4], float (&ey)[4], float (&c0)[4])
{
    #pragma unroll
    for (int k = 0; k < 4; ++k) {
        const int k2 = (k + 1) & 3;
        ex[k] = vx[k2] - vx[k];
        ey[k] = vy[k2] - vy[k];
        c0[k] = fmaf(ex[k], vy[k], -(ey[k] * vx[k]));
    }
}

__global__ __launch_bounds__(TPB, 4) void obb_fused(
    const float4* __restrict__ pred, const float4* __restrict__ gt,
    const int* __restrict__ mask,
    float2* __restrict__ partial, unsigned* __restrict__ counter,
    float* __restrict__ out, int nblocks, int total)
{
    __shared__ float  red_l[TPB / 64], red_m[TPB / 64];
    __shared__ double dred_l[TPB / 64], dred_m[TPB / 64];
    __shared__ int    is_last;

    const int idx = blockIdx.x * TPB + threadIdx.x;
    float loss = 0.f, mval = 0.f;

    if (idx < total) {
        const float4 p01 = pred[idx * 2], p23 = pred[idx * 2 + 1];
        const float4 g01 = gt[idx * 2],   g23 = gt[idx * 2 + 1];

        // IoU is invariant under the reference's (x,y)->(W*x,H*y) scaling
        // (every polygon area scales by W*H), so image_size is not needed.
        float px[4] = {p01.x, p01.z, p23.x, p23.z};
        float py[4] = {p01.y, p01.w, p23.y, p23.w};
        float gx[4] = {g01.x, g01.z, g23.x, g23.z};
        float gy[4] = {g01.y, g01.w, g23.y, g23.w};

        float ap_s = 0.f, ag_s = 0.f;               // shoelace, cnt=4
        #pragma unroll
        for (int i = 0; i < 4; ++i) {
            const int j = (i + 1) & 3;
            ap_s += px[i] * py[j] - py[i] * px[j];
            ag_s += gx[i] * gy[j] - gy[i] * gx[j];
        }
        ap_s *= 0.5f;  ag_s *= 0.5f;

        // force both quads CCW (intersection needs consistent orientation)
        if (ap_s < 0.f) {
            float t;
            t = px[0]; px[0] = px[3]; px[3] = t;  t = py[0]; py[0] = py[3]; py[3] = t;
            t = px[1]; px[1] = px[2]; px[2] = t;  t = py[1]; py[1] = py[2]; py[2] = t;
        }
        if (ag_s < 0.f) {
            float t;
            t = gx[0]; gx[0] = gx[3]; gx[3] = t;  t = gy[0]; gy[0] = gy[3]; gy[3] = t;
            t = gx[1]; gx[1] = gx[2]; gx[2] = t;  t = gy[1]; gy[1] = gy[2]; gy[2] = t;
        }

        float pex[4], pey[4], pc0[4], gex[4], gey[4], gc0[4];
        make_lines(px, py, pex, pey, pc0);
        make_lines(gx, gy, gex, gey, gc0);

        const float a2 = edge_pieces<true >(px, py, gex, gey, gc0)   // P edges in Q
                       + edge_pieces<false>(gx, gy, pex, pey, pc0);  // Q edges in P

        const float inter = 0.5f * fabsf(a2);
        const float ap = fabsf(ap_s), ag = fabsf(ag_s);
        const float uni = ap + ag - inter;
        const float iou = (uni > 0.f) ? inter * __builtin_amdgcn_rcpf(uni) : 0.f;
        mval = (mask[idx] != 0) ? 1.f : 0.f;
        loss = (1.f - iou) * mval;
    }

    // per-block reduction: wave shuffle, then cross-wave LDS
    float l = loss, m = mval;
    #pragma unroll
    for (int off = 32; off > 0; off >>= 1) {
        l += __shfl_down(l, off, 64);
        m += __shfl_down(m, off, 64);
    }
    const int wid  = threadIdx.x >> 6;
    const int lane = threadIdx.x & 63;
    if (lane == 0) { red_l[wid] = l; red_m[wid] = m; }
    __syncthreads();

    if (threadIdx.x == 0) {
        const float L = red_l[0] + red_l[1] + red_l[2] + red_l[3];
        const float M = red_m[0] + red_m[1] + red_m[2] + red_m[3];
        const float2 v = make_float2(L, M);
        unsigned long long u;
        __builtin_memcpy(&u, &v, 8);
        __hip_atomic_store((unsigned long long*)(partial + blockIdx.x), u,
                           __ATOMIC_RELEASE, __HIP_MEMORY_SCOPE_AGENT);
        const unsigned old = __hip_atomic_fetch_add(counter, 1u, __ATOMIC_ACQ_REL,
                                                    __HIP_MEMORY_SCOPE_AGENT);
        is_last = (old == (unsigned)(nblocks - 1)) ? 1 : 0;
    }
    __syncthreads();

    // last block to finish reduces all partials in a FIXED order (deterministic)
    if (is_last) {
        double dl = 0.0, dm = 0.0;
        for (int i = threadIdx.x; i < nblocks; i += TPB) {
            const unsigned long long u = __hip_atomic_load(
                (const unsigned long long*)(partial + i), __ATOMIC_ACQUIRE,
                __HIP_MEMORY_SCOPE_AGENT);
            float2 v;
            __builtin_memcpy(&v, &u, 8);
            dl += (double)v.x;
            dm += (double)v.y;
        }
        #pragma unroll
        for (int off = 32; off > 0; off >>= 1) {
            dl += __shfl_down(dl, off, 64);
            dm += __shfl_down(dm, off, 64);
        }
        if (lane == 0) { dred_l[wid] = dl; dred_m[wid] = dm; }
        __syncthreads();
        if (threadIdx.x == 0) {
            const double L = dred_l[0] + dred_l[1] + dred_l[2] + dred_l[3];
            const double M = dred_m[0] + dred_m[1] + dred_m[2] + dred_m[3];
            const double mean = L / (M > 1.0 ? M : 1.0);
            out[0] = (M > 0.0) ? (float)mean : 0.f;
        }
    }
}

extern "C" void kernel_launch(void* const* d_in, const int* in_sizes, int n_in,
                              void* d_out, int out_size, void* d_ws, size_t ws_size,
                              hipStream_t stream)
{
    const float4* pred = (const float4*)d_in[0];   // (B,N,8) f32
    const float4* gt   = (const float4*)d_in[1];   // (B,N,8) f32
    const int* mask    = (const int*)d_in[3];      // (B,N) bool->i32
    float* out = (float*)d_out;                    // scalar f32

    const int total   = in_sizes[0] / 8;           // B*N
    const int nblocks = (total + TPB - 1) / TPB;

    unsigned char* ws = (unsigned char*)d_ws;
    float2*   partial = (float2*)ws;                               // nblocks*8 B
    unsigned* counter = (unsigned*)(ws + (size_t)nblocks * 8);     // 4 B

    hipMemsetAsync(counter, 0, sizeof(unsigned), stream);
    obb_fused<<<nblocks, TPB, 0, stream>>>(pred, gt, mask, partial, counter,
                                           out, nblocks, total);
}

// Round 5
// 17.527 us; speedup vs baseline: 4.3829x; 4.3829x over previous
//
#include <hip/hip_runtime.h>

#define TPB 256

// Sum over the 4 edges (A->B) of CCW polygon V of (t1-t0)*cross(A,B), where
// [t0,t1] ⊆ [0,1] is the parameter interval of the edge inside the CCW clip
// quad given by lines d(X) = ex*X.y - ey*X.x - c0 >= 0.  Summing this for
// (P-edges clipped by Q) and (Q-edges clipped by P) gives 2*area(P∩Q).
//
// Interval form: d(t) = dA - t*D with D = dA-dB.  D>0 -> t is an upper bound,
// D<0 -> t is a lower bound.  PROT=true (P-pass): degenerate |D|<eps keeps the
// edge when dA>=0 (ties count as inside); PROT=false (Q-pass): degenerate
// edges are dropped (ties outside) so coincident boundaries aren't double-counted.
template<bool PROT>
__device__ __forceinline__ float edge_pieces(
    const float (&vx)[4], const float (&vy)[4],
    const float (&ex)[4], const float (&ey)[4], const float (&c0)[4])
{
    float d[4][4];
    #pragma unroll
    for (int i = 0; i < 4; ++i)
        #pragma unroll
        for (int k = 0; k < 4; ++k)
            d[i][k] = fmaf(ex[k], vy[i], -fmaf(ey[k], vx[i], c0[k]));

    float sum = 0.f;
    #pragma unroll
    for (int i = 0; i < 4; ++i) {
        const int j = (i + 1) & 3;
        const float cr = fmaf(vx[i], vy[j], -(vy[i] * vx[j]));
        float lo = 0.f, hi = 1.f;
        #pragma unroll
        for (int k = 0; k < 4; ++k) {
            const float dA = d[i][k], dB = d[j][k];
            const float D  = dA - dB;
            float Dt;
            if (PROT) {
                const float eps = (dA >= 0.f) ? -1e-12f : 1e-12f;
                Dt = (fabsf(D) < 1e-12f) ? eps : D;
            } else {
                Dt = (fabsf(D) < 1e-12f) ? 1e-12f : D;
            }
            const float t  = dA * __builtin_amdgcn_rcpf(Dt);
            const bool  up = Dt > 0.f;
            const float h2 = fminf(hi, t);
            const float l2 = fmaxf(lo, t);
            hi = up ? h2 : hi;
            lo = up ? lo : l2;
        }
        sum = fmaf(fmaxf(hi - lo, 0.f), cr, sum);
    }
    return sum;
}

__device__ __forceinline__ void make_lines(
    const float (&vx)[4], const float (&vy)[4],
    float (&ex)[4], float (&ey)[4], float (&c0)[4])
{
    #pragma unroll
    for (int k = 0; k < 4; ++k) {
        const int k2 = (k + 1) & 3;
        ex[k] = vx[k2] - vx[k];
        ey[k] = vy[k2] - vy[k];
        c0[k] = fmaf(ex[k], vy[k], -(ey[k] * vx[k]));
    }
}

// 1 - IoU for one pair (IoU is invariant under the reference's per-image
// (x,y)->(W*x,H*y) scaling -- all areas scale by W*H -- so image_size is
// not needed).
__device__ __forceinline__ float pair_loss(const float4 p01, const float4 p23,
                                           const float4 g01, const float4 g23)
{
    float px[4] = {p01.x, p01.z, p23.x, p23.z};
    float py[4] = {p01.y, p01.w, p23.y, p23.w};
    float gx[4] = {g01.x, g01.z, g23.x, g23.z};
    float gy[4] = {g01.y, g01.w, g23.y, g23.w};

    float ap_s = 0.f, ag_s = 0.f;               // shoelace, cnt=4
    #pragma unroll
    for (int i = 0; i < 4; ++i) {
        const int j = (i + 1) & 3;
        ap_s += px[i] * py[j] - py[i] * px[j];
        ag_s += gx[i] * gy[j] - gy[i] * gx[j];
    }
    ap_s *= 0.5f;  ag_s *= 0.5f;

    // force both quads CCW (intersection needs consistent orientation)
    if (ap_s < 0.f) {
        float t;
        t = px[0]; px[0] = px[3]; px[3] = t;  t = py[0]; py[0] = py[3]; py[3] = t;
        t = px[1]; px[1] = px[2]; px[2] = t;  t = py[1]; py[1] = py[2]; py[2] = t;
    }
    if (ag_s < 0.f) {
        float t;
        t = gx[0]; gx[0] = gx[3]; gx[3] = t;  t = gy[0]; gy[0] = gy[3]; gy[3] = t;
        t = gx[1]; gx[1] = gx[2]; gx[2] = t;  t = gy[1]; gy[1] = gy[2]; gy[2] = t;
    }

    float pex[4], pey[4], pc0[4], gex[4], gey[4], gc0[4];
    make_lines(px, py, pex, pey, pc0);
    make_lines(gx, gy, gex, gey, gc0);

    const float a2 = edge_pieces<true >(px, py, gex, gey, gc0)   // P edges in Q
                   + edge_pieces<false>(gx, gy, pex, pey, pc0);  // Q edges in P

    const float inter = 0.5f * fabsf(a2);
    const float ap = fabsf(ap_s), ag = fabsf(ag_s);
    const float uni = ap + ag - inter;
    const float iou = (uni > 0.f) ? inter * __builtin_amdgcn_rcpf(uni) : 0.f;
    return 1.f - iou;
}

// Two independent pairs per thread (pair t0 and t0+half): dependency-free
// instruction streams fill the rcp / cmp-cndmask latency bubbles and give the
// SLP vectorizer adjacent identical fp32 ops to pack (v_pk_*_f32).
__global__ __launch_bounds__(TPB) void obb_pair_kernel(
    const float4* __restrict__ pred, const float4* __restrict__ gt,
    const int* __restrict__ mask, float2* __restrict__ partial,
    int half, int total)
{
    __shared__ float red_l[TPB / 64], red_m[TPB / 64];

    const int t0 = blockIdx.x * TPB + threadIdx.x;

    float lacc = 0.f, macc = 0.f;
    #pragma unroll
    for (int u = 0; u < 2; ++u) {
        const int idx = t0 + u * half;
        const bool ok = (u == 0) ? (t0 < half) : (idx < total);
        if (ok) {
            const float4 p01 = pred[idx * 2], p23 = pred[idx * 2 + 1];
            const float4 g01 = gt[idx * 2],   g23 = gt[idx * 2 + 1];
            const float mval = (mask[idx] != 0) ? 1.f : 0.f;
            const float loss = pair_loss(p01, p23, g01, g23);
            lacc = fmaf(loss, mval, lacc);
            macc += mval;
        }
    }

    // deterministic block reduction: wave shuffle then cross-wave LDS
    float l = lacc, m = macc;
    #pragma unroll
    for (int off = 32; off > 0; off >>= 1) {
        l += __shfl_down(l, off, 64);
        m += __shfl_down(m, off, 64);
    }
    const int wid  = threadIdx.x >> 6;
    const int lane = threadIdx.x & 63;
    if (lane == 0) { red_l[wid] = l; red_m[wid] = m; }
    __syncthreads();
    if (threadIdx.x == 0) {
        const float L = red_l[0] + red_l[1] + red_l[2] + red_l[3];
        const float M = red_m[0] + red_m[1] + red_m[2] + red_m[3];
        partial[blockIdx.x] = make_float2(L, M);
    }
}

__global__ __launch_bounds__(256) void obb_finalize(
    const float2* __restrict__ partial, int nb, float* __restrict__ out)
{
    __shared__ double sl[256], sm[256];
    double l = 0.0, m = 0.0;
    for (int i = threadIdx.x; i < nb; i += 256) {
        const float2 v = partial[i];
        l += (double)v.x;
        m += (double)v.y;
    }
    sl[threadIdx.x] = l;
    sm[threadIdx.x] = m;
    __syncthreads();
    for (int s = 128; s > 0; s >>= 1) {
        if (threadIdx.x < s) {
            sl[threadIdx.x] += sl[threadIdx.x + s];
            sm[threadIdx.x] += sm[threadIdx.x + s];
        }
        __syncthreads();
    }
    if (threadIdx.x == 0) {
        const double nval = sm[0];
        const double mean = sl[0] / (nval > 1.0 ? nval : 1.0);
        out[0] = (nval > 0.0) ? (float)mean : 0.f;
    }
}

extern "C" void kernel_launch(void* const* d_in, const int* in_sizes, int n_in,
                              void* d_out, int out_size, void* d_ws, size_t ws_size,
                              hipStream_t stream)
{
    const float4* pred = (const float4*)d_in[0];   // (B,N,8) f32
    const float4* gt   = (const float4*)d_in[1];   // (B,N,8) f32
    const int* mask    = (const int*)d_in[3];      // (B,N) bool->i32
    float* out = (float*)d_out;                    // scalar f32

    const int total  = in_sizes[0] / 8;            // B*N
    const int half   = (total + 1) / 2;
    const int blocks = (half + TPB - 1) / TPB;

    float2* partial = (float2*)d_ws;               // blocks * 8 B

    obb_pair_kernel<<<blocks, TPB, 0, stream>>>(pred, gt, mask, partial,
                                                half, total);
    obb_finalize<<<1, 256, 0, stream>>>(partial, blocks, out);
}